// Round 1
// baseline (334.128 us; speedup 1.0000x reference)
//
#include <hip/hip_runtime.h>
#include <cstdint>
#include <cstddef>

#define AS1 __attribute__((address_space(1)))
#define AS3 __attribute__((address_space(3)))

typedef __bf16 bf16x8 __attribute__((ext_vector_type(8)));
typedef float  f32x16 __attribute__((ext_vector_type(16)));

#define MDIM 16384   // B*S
#define NDIM 1024    // EMBED
#define KDIM 4096    // FFN
#define NQ   8

#define BM 128
#define BN 128
#define BK 64        // bf16 elems per row chunk (128 B)

// ---------------- W2 fp32 -> bf16 (8 elems/thread) ----------------
__global__ __launch_bounds__(256) void conv_w2_kernel(const float* __restrict__ W2,
                                                      __bf16* __restrict__ W2b) {
    size_t base = ((size_t)blockIdx.x * 256 + threadIdx.x) * 8;
    float4 a = *(const float4*)(W2 + base);
    float4 b = *(const float4*)(W2 + base + 4);
    bf16x8 v;
    v[0] = (__bf16)a.x; v[1] = (__bf16)a.y; v[2] = (__bf16)a.z; v[3] = (__bf16)a.w;
    v[4] = (__bf16)b.x; v[5] = (__bf16)b.y; v[6] = (__bf16)b.z; v[7] = (__bf16)b.w;
    *(bf16x8*)(W2b + base) = v;
}

// ------- H = relu( (cos(x[:, :8]) * cos(theta)) @ W1^T + b1 )  -> bf16 -------
// block = 256 threads, handles 32 rows x all 4096 f. Thread t covers f = j*256+t.
__global__ __launch_bounds__(256) void qh_kernel(const float* __restrict__ x,
                                                 const float* __restrict__ theta,
                                                 const float* __restrict__ W1,
                                                 const float* __restrict__ b1,
                                                 __bf16* __restrict__ H) {
    const int t  = threadIdx.x;
    const int m0 = blockIdx.x * 32;

    float ct[NQ];
#pragma unroll
    for (int i = 0; i < NQ; ++i) ct[i] = __cosf(theta[i]);

#pragma unroll 1
    for (int rc = 0; rc < 4; ++rc) {           // 4 chunks of 8 rows
        const int mbase = m0 + rc * 8;
        float q[8][NQ];
#pragma unroll
        for (int r = 0; r < 8; ++r) {
            const float4 xa = *(const float4*)(x + (size_t)(mbase + r) * 1024);
            const float4 xb = *(const float4*)(x + (size_t)(mbase + r) * 1024 + 4);
            q[r][0] = __cosf(xa.x) * ct[0];
            q[r][1] = __cosf(xa.y) * ct[1];
            q[r][2] = __cosf(xa.z) * ct[2];
            q[r][3] = __cosf(xa.w) * ct[3];
            q[r][4] = __cosf(xb.x) * ct[4];
            q[r][5] = __cosf(xb.y) * ct[5];
            q[r][6] = __cosf(xb.z) * ct[6];
            q[r][7] = __cosf(xb.w) * ct[7];
        }
#pragma unroll 1
        for (int j = 0; j < 16; ++j) {
            const int f = j * 256 + t;
            const float4 wa = *(const float4*)(W1 + (size_t)f * NQ);
            const float4 wb = *(const float4*)(W1 + (size_t)f * NQ + 4);
            const float bb = b1[f];
#pragma unroll
            for (int r = 0; r < 8; ++r) {
                float a = bb
                        + q[r][0] * wa.x + q[r][1] * wa.y + q[r][2] * wa.z + q[r][3] * wa.w
                        + q[r][4] * wb.x + q[r][5] * wb.y + q[r][6] * wb.z + q[r][7] * wb.w;
                a = a > 0.f ? a : 0.f;
                H[(size_t)(mbase + r) * KDIM + f] = (__bf16)a;
            }
        }
    }
}

// ---------------- C[M,N] = A[M,K] * B[N,K]^T + bias, bf16 MFMA ----------------
// 128x128 block tile, 4 waves each 64x64 (2x2 of 32x32x16 MFMA), BK=64.
// LDS layout XOR-swizzled in 16B units: addr16(row, u) = row*8 + (u ^ (row&7)).
// global_load_lds writes wave-uniform base + lane*16: lane i -> row i>>3, unit i&7,
// so lane i must SOURCE logical unit (i&7)^(i>>3) — per-lane global addr handles it.
__global__ __launch_bounds__(256) void gemm_bt_kernel(const __bf16* __restrict__ A,
                                                      const __bf16* __restrict__ B,
                                                      const float* __restrict__ bias,
                                                      float* __restrict__ C) {
    __shared__ __align__(16) __bf16 Al[BM * BK];
    __shared__ __align__(16) __bf16 Bl[BN * BK];

    const int tid  = threadIdx.x;
    const int wave = tid >> 6;
    const int lane = tid & 63;
    const int bm = blockIdx.x;
    const int bn = blockIdx.y;

    // ---- staging addresses (wave stages rows [wave*32, wave*32+32), 4 chunks of 8 rows)
    const int lr = lane >> 3;            // row within 8-row chunk
    const int ul = (lane & 7) ^ lr;      // logical 16B-unit to source (swizzle)
    const size_t arow = (size_t)(bm * BM + wave * 32 + lr);
    const size_t brow = (size_t)(bn * BN + wave * 32 + lr);
    const __bf16* gA0 = A + arow * KDIM + ul * 8;
    const __bf16* gB0 = B + brow * KDIM + ul * 8;
    __bf16* lA0 = &Al[(wave * 32) * BK];
    __bf16* lB0 = &Bl[(wave * 32) * BK];

    // ---- fragment indices
    const int fl = lane & 31;            // m or n within a 32-tile
    const int fq = lane >> 5;            // selects 8-k half
    const int sw = fl & 7;               // LDS read swizzle
    const int ma[2] = { (wave & 1) * 64 + fl, (wave & 1) * 64 + 32 + fl };
    const int na[2] = { (wave >> 1) * 64 + fl, (wave >> 1) * 64 + 32 + fl };

    f32x16 acc[2][2] = {};

    for (int kt = 0; kt < KDIM; kt += BK) {
        __syncthreads();   // previous compute done before overwriting LDS
#pragma unroll
        for (int c = 0; c < 4; ++c) {
            __builtin_amdgcn_global_load_lds((AS1 void*)(gA0 + (size_t)c * 8 * KDIM + kt),
                                             (AS3 void*)(lA0 + c * 8 * BK), 16, 0, 0);
            __builtin_amdgcn_global_load_lds((AS1 void*)(gB0 + (size_t)c * 8 * KDIM + kt),
                                             (AS3 void*)(lB0 + c * 8 * BK), 16, 0, 0);
        }
        __syncthreads();   // drains vmcnt -> LDS tiles complete
#pragma unroll
        for (int t4 = 0; t4 < 4; ++t4) {  // 4 k-steps of 16
            bf16x8 af[2], bfr[2];
            const int u = (t4 * 2 + fq) ^ sw;
#pragma unroll
            for (int i = 0; i < 2; ++i) {
                af[i]  = *(const bf16x8*)&Al[ma[i] * BK + u * 8];
                bfr[i] = *(const bf16x8*)&Bl[na[i] * BK + u * 8];
            }
            acc[0][0] = __builtin_amdgcn_mfma_f32_32x32x16_bf16(af[0], bfr[0], acc[0][0], 0, 0, 0);
            acc[0][1] = __builtin_amdgcn_mfma_f32_32x32x16_bf16(af[0], bfr[1], acc[0][1], 0, 0, 0);
            acc[1][0] = __builtin_amdgcn_mfma_f32_32x32x16_bf16(af[1], bfr[0], acc[1][0], 0, 0, 0);
            acc[1][1] = __builtin_amdgcn_mfma_f32_32x32x16_bf16(af[1], bfr[1], acc[1][1], 0, 0, 0);
        }
    }

    // ---- epilogue: C/D layout col=lane&31, row=(reg&3)+8*(reg>>2)+4*(lane>>5)
    const int cm0 = bm * BM + (wave & 1) * 64;
    const int cn0 = bn * BN + (wave >> 1) * 64;
#pragma unroll
    for (int i = 0; i < 2; ++i) {
#pragma unroll
        for (int j = 0; j < 2; ++j) {
            const int col = cn0 + j * 32 + fl;
            const float bv = bias[col];
#pragma unroll
            for (int r = 0; r < 16; ++r) {
                const int row = cm0 + i * 32 + (r & 3) + 8 * (r >> 2) + 4 * fq;
                C[(size_t)row * NDIM + col] = acc[i][j][r] + bv;
            }
        }
    }
}

extern "C" void kernel_launch(void* const* d_in, const int* in_sizes, int n_in,
                              void* d_out, int out_size, void* d_ws, size_t ws_size,
                              hipStream_t stream) {
    const float* x     = (const float*)d_in[0];
    const float* theta = (const float*)d_in[1];
    const float* W1    = (const float*)d_in[2];
    const float* b1    = (const float*)d_in[3];
    const float* W2    = (const float*)d_in[4];
    const float* b2    = (const float*)d_in[5];
    float* out = (float*)d_out;

    __bf16* H   = (__bf16*)d_ws;                                    // 16384*4096*2 = 128 MiB
    __bf16* W2b = (__bf16*)((char*)d_ws + (size_t)MDIM * KDIM * 2); // + 8 MiB

    conv_w2_kernel<<<(KDIM * NDIM) / (256 * 8), 256, 0, stream>>>(W2, W2b);
    qh_kernel<<<MDIM / 32, 256, 0, stream>>>(x, theta, W1, b1, H);
    gemm_bt_kernel<<<dim3(MDIM / BM, NDIM / BN), 256, 0, stream>>>(H, W2b, b2, out);
}

// Round 2
// 332.099 us; speedup vs baseline: 1.0061x; 1.0061x over previous
//
#include <hip/hip_runtime.h>
#include <cstdint>
#include <cstddef>

#define AS1 __attribute__((address_space(1)))
#define AS3 __attribute__((address_space(3)))

typedef __bf16 bf16x8 __attribute__((ext_vector_type(8)));
typedef float  f32x16 __attribute__((ext_vector_type(16)));

#define MDIM 16384   // B*S
#define NDIM 1024    // EMBED
#define KDIM 4096    // FFN
#define NQ   8

#define BM 256
#define BN 256
#define BK 64        // bf16 elems per K-chunk (128 B per row)

// ---------------- W2 fp32 -> bf16 (8 elems/thread) ----------------
__global__ __launch_bounds__(256) void conv_w2_kernel(const float* __restrict__ W2,
                                                      __bf16* __restrict__ W2b) {
    size_t base = ((size_t)blockIdx.x * 256 + threadIdx.x) * 8;
    float4 a = *(const float4*)(W2 + base);
    float4 b = *(const float4*)(W2 + base + 4);
    bf16x8 v;
    v[0] = (__bf16)a.x; v[1] = (__bf16)a.y; v[2] = (__bf16)a.z; v[3] = (__bf16)a.w;
    v[4] = (__bf16)b.x; v[5] = (__bf16)b.y; v[6] = (__bf16)b.z; v[7] = (__bf16)b.w;
    *(bf16x8*)(W2b + base) = v;
}

// ------- H = relu( (cos(x[:, :8]) * cos(theta)) @ W1^T + b1 )  -> bf16 -------
// Thread t owns 8 consecutive f (W1 rows held in registers for the whole
// block); loops over rows writing one bf16x8 (16 B/lane) per row.
#define QROWS 64
__global__ __launch_bounds__(256) void qh_kernel(const float* __restrict__ x,
                                                 const float* __restrict__ theta,
                                                 const float* __restrict__ W1,
                                                 const float* __restrict__ b1,
                                                 __bf16* __restrict__ H) {
    const int t  = threadIdx.x;
    const int f0 = blockIdx.y * 2048 + t * 8;
    const int r0 = blockIdx.x * QROWS;

    float w[8][8];
#pragma unroll
    for (int fr = 0; fr < 8; ++fr) {
        float4 a = *(const float4*)(W1 + (size_t)(f0 + fr) * NQ);
        float4 b = *(const float4*)(W1 + (size_t)(f0 + fr) * NQ + 4);
        w[fr][0] = a.x; w[fr][1] = a.y; w[fr][2] = a.z; w[fr][3] = a.w;
        w[fr][4] = b.x; w[fr][5] = b.y; w[fr][6] = b.z; w[fr][7] = b.w;
    }
    float bias[8];
    {
        float4 a = *(const float4*)(b1 + f0);
        float4 b = *(const float4*)(b1 + f0 + 4);
        bias[0] = a.x; bias[1] = a.y; bias[2] = a.z; bias[3] = a.w;
        bias[4] = b.x; bias[5] = b.y; bias[6] = b.z; bias[7] = b.w;
    }
    float ct[NQ];
#pragma unroll
    for (int i = 0; i < NQ; ++i) ct[i] = __cosf(theta[i]);

#pragma unroll 1
    for (int r = 0; r < QROWS; ++r) {
        const float* xr = x + (size_t)(r0 + r) * 1024;
        const float4 xa = *(const float4*)xr;
        const float4 xb = *(const float4*)(xr + 4);
        float q[8];
        q[0] = __cosf(xa.x) * ct[0]; q[1] = __cosf(xa.y) * ct[1];
        q[2] = __cosf(xa.z) * ct[2]; q[3] = __cosf(xa.w) * ct[3];
        q[4] = __cosf(xb.x) * ct[4]; q[5] = __cosf(xb.y) * ct[5];
        q[6] = __cosf(xb.z) * ct[6]; q[7] = __cosf(xb.w) * ct[7];
        bf16x8 o;
#pragma unroll
        for (int fr = 0; fr < 8; ++fr) {
            float a = bias[fr];
#pragma unroll
            for (int i = 0; i < 8; ++i) a += q[i] * w[fr][i];
            a = fmaxf(a, 0.f);
            o[fr] = (__bf16)a;
        }
        *(bf16x8*)(H + (size_t)(r0 + r) * KDIM + f0) = o;
    }
}

// ---------------- C[M,N] = A[M,K] * B[N,K]^T + bias, bf16 MFMA ----------------
// 256x256 block tile, 4 waves (2x2), each wave 128x128 = 4x4 of 32x32x16 MFMA.
// 2 MFMA per ds_read_b128 (vs 1 before) -> halves LDS pipe pressure.
// LDS XOR-swizzled in 16B units: pos(row, u) = u ^ (row & 7); global_load_lds
// writes wave-uniform base + lane*16, so lane i sources logical unit
// (i&7)^(i>>3) via its per-lane global address.
__global__ __launch_bounds__(256, 1) void gemm_bt_kernel(const __bf16* __restrict__ A,
                                                         const __bf16* __restrict__ B,
                                                         const float* __restrict__ bias,
                                                         float* __restrict__ C) {
    __shared__ __align__(16) __bf16 Al[BM * BK];
    __shared__ __align__(16) __bf16 Bl[BN * BK];

    const int tid  = threadIdx.x;
    const int wave = tid >> 6;
    const int lane = tid & 63;
    const int bm = blockIdx.x;
    const int bn = blockIdx.y;

    // ---- staging: wave stages A rows [wave*64, +64) and B rows likewise,
    //      8 chunks of 8 rows, 1 KB (16 B x 64 lanes) per global_load_lds.
    const int lr = lane >> 3;            // row within 8-row chunk
    const int ul = (lane & 7) ^ lr;      // logical 16B unit to source (swizzle)
    const __bf16* gA0 = A + (size_t)(bm * BM + wave * 64 + lr) * KDIM + ul * 8;
    const __bf16* gB0 = B + (size_t)(bn * BN + wave * 64 + lr) * KDIM + ul * 8;
    __bf16* lA0 = &Al[(wave * 64) * BK];
    __bf16* lB0 = &Bl[(wave * 64) * BK];

    // ---- fragment indices
    const int fl = lane & 31;            // m or n within a 32-tile
    const int fq = lane >> 5;            // 8-k half
    const int sw = fl & 7;               // read-side swizzle (row & 7 == fl & 7)
    const int wm = (wave & 1) * 128;
    const int wn = (wave >> 1) * 128;

    f32x16 acc[4][4] = {};

    for (int kt = 0; kt < KDIM; kt += BK) {
        __syncthreads();   // previous tile's reads done before overwrite
#pragma unroll
        for (int c = 0; c < 8; ++c) {
            __builtin_amdgcn_global_load_lds((AS1 void*)(gA0 + (size_t)c * 8 * KDIM + kt),
                                             (AS3 void*)(lA0 + c * 8 * BK), 16, 0, 0);
            __builtin_amdgcn_global_load_lds((AS1 void*)(gB0 + (size_t)c * 8 * KDIM + kt),
                                             (AS3 void*)(lB0 + c * 8 * BK), 16, 0, 0);
        }
        __syncthreads();   // drains vmcnt -> tiles complete
#pragma unroll
        for (int t4 = 0; t4 < 4; ++t4) {  // 4 k-steps of 16
            const int u = ((t4 * 2 + fq) ^ sw) * 8;
            bf16x8 af[4], bfr[4];
#pragma unroll
            for (int i = 0; i < 4; ++i) {
                af[i]  = *(const bf16x8*)&Al[(wm + i * 32 + fl) * BK + u];
                bfr[i] = *(const bf16x8*)&Bl[(wn + i * 32 + fl) * BK + u];
            }
#pragma unroll
            for (int i = 0; i < 4; ++i)
#pragma unroll
                for (int j = 0; j < 4; ++j)
                    acc[i][j] = __builtin_amdgcn_mfma_f32_32x32x16_bf16(af[i], bfr[j], acc[i][j], 0, 0, 0);
        }
    }

    // ---- epilogue: C/D layout col=lane&31, row=(r&3)+8*(r>>2)+4*(lane>>5)
    const int cm0 = bm * BM + wm;
    const int cn0 = bn * BN + wn;
#pragma unroll
    for (int j = 0; j < 4; ++j) {
        const int col = cn0 + j * 32 + fl;
        const float bv = bias[col];
#pragma unroll
        for (int i = 0; i < 4; ++i)
#pragma unroll
            for (int r = 0; r < 16; ++r) {
                const int row = cm0 + i * 32 + (r & 3) + 8 * (r >> 2) + 4 * fq;
                C[(size_t)row * NDIM + col] = acc[i][j][r] + bv;
            }
    }
}

extern "C" void kernel_launch(void* const* d_in, const int* in_sizes, int n_in,
                              void* d_out, int out_size, void* d_ws, size_t ws_size,
                              hipStream_t stream) {
    const float* x     = (const float*)d_in[0];
    const float* theta = (const float*)d_in[1];
    const float* W1    = (const float*)d_in[2];
    const float* b1    = (const float*)d_in[3];
    const float* W2    = (const float*)d_in[4];
    const float* b2    = (const float*)d_in[5];
    float* out = (float*)d_out;

    __bf16* H   = (__bf16*)d_ws;                                    // 128 MiB
    __bf16* W2b = (__bf16*)((char*)d_ws + (size_t)MDIM * KDIM * 2); // + 8 MiB

    conv_w2_kernel<<<(KDIM * NDIM) / (256 * 8), 256, 0, stream>>>(W2, W2b);
    qh_kernel<<<dim3(MDIM / QROWS, KDIM / 2048), 256, 0, stream>>>(x, theta, W1, b1, H);
    gemm_bt_kernel<<<dim3(MDIM / BM, NDIM / BN), 256, 0, stream>>>(H, W2b, b2, out);
}

// Round 4
// 323.805 us; speedup vs baseline: 1.0319x; 1.0256x over previous
//
#include <hip/hip_runtime.h>
#include <cstdint>
#include <cstddef>

#define AS1 __attribute__((address_space(1)))
#define AS3 __attribute__((address_space(3)))

typedef __bf16 bf16x8 __attribute__((ext_vector_type(8)));
typedef float  f32x4  __attribute__((ext_vector_type(4)));

#define MDIM 16384   // B*S
#define NDIM 1024    // EMBED
#define KDIM 4096    // FFN
#define NQ   8

#define BM 128
#define BN 128
#define BK 64        // bf16 elems per K-chunk (8 x 16B units per row)

// ---------------- W2 fp32 -> bf16 (8 elems/thread) ----------------
__global__ __launch_bounds__(256) void conv_w2_kernel(const float* __restrict__ W2,
                                                      __bf16* __restrict__ W2b) {
    size_t base = ((size_t)blockIdx.x * 256 + threadIdx.x) * 8;
    float4 a = *(const float4*)(W2 + base);
    float4 b = *(const float4*)(W2 + base + 4);
    bf16x8 v;
    v[0] = (__bf16)a.x; v[1] = (__bf16)a.y; v[2] = (__bf16)a.z; v[3] = (__bf16)a.w;
    v[4] = (__bf16)b.x; v[5] = (__bf16)b.y; v[6] = (__bf16)b.z; v[7] = (__bf16)b.w;
    *(bf16x8*)(W2b + base) = v;
}

// ------- H = relu( (cos(x[:, :8]) * cos(theta)) @ W1^T + b1 )  -> bf16 -------
// Block = 256 threads, 32 rows. q[32][8] staged in LDS once (cos computed once
// per value, not x256). Then 2 f-chunks of 2048: thread t owns f = f0..f0+7
// with W1 rows register-pinned, loops rows reading q via LDS broadcast,
// writes one bf16x8 (16 B/lane) per row.
#define QROWS 32
__global__ __launch_bounds__(256) void qh_kernel(const float* __restrict__ x,
                                                 const float* __restrict__ theta,
                                                 const float* __restrict__ W1,
                                                 const float* __restrict__ b1,
                                                 __bf16* __restrict__ H) {
    __shared__ __align__(16) float qs[QROWS][NQ];
    const int t  = threadIdx.x;
    const int r0 = blockIdx.x * QROWS;

    // stage q: one value per thread (32 rows x 8 qubits = 256)
    {
        const int qr = t >> 3, qi = t & 7;
        const float xv = x[(size_t)(r0 + qr) * 1024 + qi];
        qs[qr][qi] = __cosf(xv) * __cosf(theta[qi]);
    }
    __syncthreads();

#pragma unroll
    for (int fc = 0; fc < 2; ++fc) {
        const int f0 = fc * 2048 + t * 8;
        float w[8][8];
#pragma unroll
        for (int fr = 0; fr < 8; ++fr) {
            float4 a = *(const float4*)(W1 + (size_t)(f0 + fr) * NQ);
            float4 b = *(const float4*)(W1 + (size_t)(f0 + fr) * NQ + 4);
            w[fr][0] = a.x; w[fr][1] = a.y; w[fr][2] = a.z; w[fr][3] = a.w;
            w[fr][4] = b.x; w[fr][5] = b.y; w[fr][6] = b.z; w[fr][7] = b.w;
        }
        float bias[8];
        {
            float4 a = *(const float4*)(b1 + f0);
            float4 b = *(const float4*)(b1 + f0 + 4);
            bias[0] = a.x; bias[1] = a.y; bias[2] = a.z; bias[3] = a.w;
            bias[4] = b.x; bias[5] = b.y; bias[6] = b.z; bias[7] = b.w;
        }
#pragma unroll 1
        for (int r = 0; r < QROWS; ++r) {
            const float4 qa = *(const float4*)&qs[r][0];   // LDS broadcast
            const float4 qb = *(const float4*)&qs[r][4];
            float q[8] = { qa.x, qa.y, qa.z, qa.w, qb.x, qb.y, qb.z, qb.w };
            bf16x8 o;
#pragma unroll
            for (int fr = 0; fr < 8; ++fr) {
                float a = bias[fr];
#pragma unroll
                for (int i = 0; i < 8; ++i) a += q[i] * w[fr][i];
                o[fr] = (__bf16)fmaxf(a, 0.f);
            }
            *(bf16x8*)(H + (size_t)(r0 + r) * KDIM + f0) = o;
        }
    }
}

// ---------------- C[M,N] = A[M,K] * B[N,K]^T + bias, bf16 MFMA ----------------
// m97 structure: 128x128 block, 4 waves (2x2), each wave 64x64 = 4x4 of
// 16x16x32 MFMA, acc = 64 VGPRs/wave. BK=64, 32 KB LDS, ~3 blocks/CU.
// Grid (bn, bm) with bn=blockIdx.x: linear id % 8 == bn == XCD, so each XCD's
// L2 keeps one 1 MB W2b strip resident while A streams from L3.
// LDS XOR-swizzle in 16B units: phys(row, u) = u ^ (row & 7). global_load_lds
// writes wave-uniform base + lane*16, so lane i sources logical unit
// (i&7)^(i>>3) via its global address.
__global__ __launch_bounds__(256, 3) void gemm_bt_kernel(const __bf16* __restrict__ A,
                                                         const __bf16* __restrict__ B,
                                                         const float* __restrict__ bias,
                                                         float* __restrict__ C) {
    __shared__ __align__(16) __bf16 Al[BM * BK];
    __shared__ __align__(16) __bf16 Bl[BN * BK];

    const int tid  = threadIdx.x;
    const int wave = tid >> 6;
    const int lane = tid & 63;
    const int bn = blockIdx.x;
    const int bm = blockIdx.y;

    // ---- staging: wave stages rows [wave*32, +32) of A and B, 4 chunks of 8 rows
    const int lr = lane >> 3;            // row within 8-row chunk
    const int ul = (lane & 7) ^ lr;      // logical 16B unit to source (swizzle)
    const __bf16* gA0 = A + (size_t)(bm * BM + wave * 32 + lr) * KDIM + ul * 8;
    const __bf16* gB0 = B + (size_t)(bn * BN + wave * 32 + lr) * KDIM + ul * 8;
    __bf16* lA0 = &Al[(wave * 32) * BK];
    __bf16* lB0 = &Bl[(wave * 32) * BK];

    // ---- fragment indices (16x16x32: lane holds [m=lane&15][k=(lane>>4)*8+j])
    const int ml = lane & 15;
    const int kq = lane >> 4;            // 0..3
    const int sw = lane & 7;             // row & 7 for fragment rows
    const int wm = (wave & 1) * 64;
    const int wn = (wave >> 1) * 64;

    f32x4 acc[4][4] = {};

    for (int kt = 0; kt < KDIM; kt += BK) {
        __syncthreads();   // previous tile's reads done before overwrite
#pragma unroll
        for (int c = 0; c < 4; ++c) {
            __builtin_amdgcn_global_load_lds((AS1 void*)(gA0 + (size_t)c * 8 * KDIM + kt),
                                             (AS3 void*)(lA0 + c * 8 * BK), 16, 0, 0);
            __builtin_amdgcn_global_load_lds((AS1 void*)(gB0 + (size_t)c * 8 * KDIM + kt),
                                             (AS3 void*)(lB0 + c * 8 * BK), 16, 0, 0);
        }
        __syncthreads();   // drains vmcnt -> tiles complete
#pragma unroll
        for (int s = 0; s < 2; ++s) {    // 2 k-steps of 32
            const int u = ((s * 4 + kq) ^ sw) * 8;
            bf16x8 afrag[4], bfrag[4];
#pragma unroll
            for (int i = 0; i < 4; ++i) {
                afrag[i] = *(const bf16x8*)&Al[(wm + i * 16 + ml) * BK + u];
                bfrag[i] = *(const bf16x8*)&Bl[(wn + i * 16 + ml) * BK + u];
            }
#pragma unroll
            for (int i = 0; i < 4; ++i)
#pragma unroll
                for (int j = 0; j < 4; ++j)
                    acc[i][j] = __builtin_amdgcn_mfma_f32_16x16x32_bf16(afrag[i], bfrag[j], acc[i][j], 0, 0, 0);
        }
    }

    // ---- epilogue: 16x16 C/D layout col=lane&15, row=(lane>>4)*4+reg
    const int cm0 = bm * BM + wm;
    const int cn0 = bn * BN + wn;
#pragma unroll
    for (int j = 0; j < 4; ++j) {
        const int col = cn0 + j * 16 + ml;
        const float bv = bias[col];
#pragma unroll
        for (int i = 0; i < 4; ++i) {
            const int row0 = cm0 + i * 16 + kq * 4;
#pragma unroll
            for (int r = 0; r < 4; ++r)
                C[(size_t)(row0 + r) * NDIM + col] = acc[i][j][r] + bv;
        }
    }
}

extern "C" void kernel_launch(void* const* d_in, const int* in_sizes, int n_in,
                              void* d_out, int out_size, void* d_ws, size_t ws_size,
                              hipStream_t stream) {
    const float* x     = (const float*)d_in[0];
    const float* theta = (const float*)d_in[1];
    const float* W1    = (const float*)d_in[2];
    const float* b1    = (const float*)d_in[3];
    const float* W2    = (const float*)d_in[4];
    const float* b2    = (const float*)d_in[5];
    float* out = (float*)d_out;

    __bf16* H   = (__bf16*)d_ws;                                    // 128 MiB
    __bf16* W2b = (__bf16*)((char*)d_ws + (size_t)MDIM * KDIM * 2); // + 8 MiB

    conv_w2_kernel<<<(KDIM * NDIM) / (256 * 8), 256, 0, stream>>>(W2, W2b);
    qh_kernel<<<MDIM / QROWS, 256, 0, stream>>>(x, theta, W1, b1, H);
    gemm_bt_kernel<<<dim3(NDIM / BN, MDIM / BM), 256, 0, stream>>>(H, W2b, b2, out);
}

// Round 5
// 289.045 us; speedup vs baseline: 1.1560x; 1.1203x over previous
//
#include <hip/hip_runtime.h>
#include <cstdint>
#include <cstddef>

#define AS1 __attribute__((address_space(1)))
#define AS3 __attribute__((address_space(3)))

typedef __bf16 bf16x8 __attribute__((ext_vector_type(8)));
typedef float  f32x4  __attribute__((ext_vector_type(4)));

#define MDIM 16384   // B*S
#define NDIM 1024    // EMBED
#define KDIM 4096    // FFN
#define NQ   8

#define BM 128
#define BN 128
#define BK 64        // bf16 elems per K-chunk (8 x 16B units per row)

// ---------------- W2 fp32 -> bf16 (8 elems/thread) ----------------
__global__ __launch_bounds__(256) void conv_w2_kernel(const float* __restrict__ W2,
                                                      __bf16* __restrict__ W2b) {
    size_t base = ((size_t)blockIdx.x * 256 + threadIdx.x) * 8;
    float4 a = *(const float4*)(W2 + base);
    float4 b = *(const float4*)(W2 + base + 4);
    bf16x8 v;
    v[0] = (__bf16)a.x; v[1] = (__bf16)a.y; v[2] = (__bf16)a.z; v[3] = (__bf16)a.w;
    v[4] = (__bf16)b.x; v[5] = (__bf16)b.y; v[6] = (__bf16)b.z; v[7] = (__bf16)b.w;
    *(bf16x8*)(W2b + base) = v;
}

// ------- H = relu( (cos(x[:, :8]) * cos(theta)) @ W1^T + b1 )  -> bf16 -------
#define QROWS 32
__global__ __launch_bounds__(256) void qh_kernel(const float* __restrict__ x,
                                                 const float* __restrict__ theta,
                                                 const float* __restrict__ W1,
                                                 const float* __restrict__ b1,
                                                 __bf16* __restrict__ H) {
    __shared__ __align__(16) float qs[QROWS][NQ];
    const int t  = threadIdx.x;
    const int r0 = blockIdx.x * QROWS;

    {
        const int qr = t >> 3, qi = t & 7;
        const float xv = x[(size_t)(r0 + qr) * 1024 + qi];
        qs[qr][qi] = __cosf(xv) * __cosf(theta[qi]);
    }
    __syncthreads();

#pragma unroll
    for (int fc = 0; fc < 2; ++fc) {
        const int f0 = fc * 2048 + t * 8;
        float w[8][8];
#pragma unroll
        for (int fr = 0; fr < 8; ++fr) {
            float4 a = *(const float4*)(W1 + (size_t)(f0 + fr) * NQ);
            float4 b = *(const float4*)(W1 + (size_t)(f0 + fr) * NQ + 4);
            w[fr][0] = a.x; w[fr][1] = a.y; w[fr][2] = a.z; w[fr][3] = a.w;
            w[fr][4] = b.x; w[fr][5] = b.y; w[fr][6] = b.z; w[fr][7] = b.w;
        }
        float bias[8];
        {
            float4 a = *(const float4*)(b1 + f0);
            float4 b = *(const float4*)(b1 + f0 + 4);
            bias[0] = a.x; bias[1] = a.y; bias[2] = a.z; bias[3] = a.w;
            bias[4] = b.x; bias[5] = b.y; bias[6] = b.z; bias[7] = b.w;
        }
#pragma unroll 1
        for (int r = 0; r < QROWS; ++r) {
            const float4 qa = *(const float4*)&qs[r][0];   // LDS broadcast
            const float4 qb = *(const float4*)&qs[r][4];
            float q[8] = { qa.x, qa.y, qa.z, qa.w, qb.x, qb.y, qb.z, qb.w };
            bf16x8 o;
#pragma unroll
            for (int fr = 0; fr < 8; ++fr) {
                float a = bias[fr];
#pragma unroll
                for (int i = 0; i < 8; ++i) a += q[i] * w[fr][i];
                o[fr] = (__bf16)fmaxf(a, 0.f);
            }
            *(bf16x8*)(H + (size_t)(r0 + r) * KDIM + f0) = o;
        }
    }
}

// ---------------- C[M,N] = A[M,K] * B[N,K]^T + bias, bf16 MFMA ----------------
// m97 structure: 128x128 block, 4 waves (2x2), each wave 64x64 = 4x4 of
// 16x16x32 MFMA. BK=64, 32 KB LDS, ~3 blocks/CU.
// XCD-affine 1-D grid: xcd=id%8, s=id/8, bn=s%8 (FASTEST), bm=xcd*16+s/8.
// -> all 8 bn-blocks of one bm are on the SAME XCD and adjacent in dispatch
// order, so each 1 MB A-strip is HBM-fetched once and L2-served 8x.
// (Round-3's bn=id%8 put them on 8 different XCDs -> 534 MB fetch, 4.2x A.)
// LDS XOR-swizzle in 16B units: phys(row, u) = u ^ (row & 7). global_load_lds
// writes wave-uniform base + lane*16, so lane i sources logical unit
// (i&7)^(i>>3) via its global address.
__global__ __launch_bounds__(256, 3) void gemm_bt_kernel(const __bf16* __restrict__ A,
                                                         const __bf16* __restrict__ B,
                                                         const float* __restrict__ bias,
                                                         float* __restrict__ C) {
    __shared__ __align__(16) __bf16 Al[BM * BK];
    __shared__ __align__(16) __bf16 Bl[BN * BK];

    const int tid  = threadIdx.x;
    const int wave = tid >> 6;
    const int lane = tid & 63;
    const int id   = blockIdx.x;
    const int xcd  = id & 7;
    const int s    = id >> 3;
    const int bn   = s & 7;
    const int bm   = xcd * 16 + (s >> 3);

    // ---- staging: wave stages rows [wave*32, +32) of A and B, 4 chunks of 8 rows
    const int lr = lane >> 3;            // row within 8-row chunk
    const int ul = (lane & 7) ^ lr;      // logical 16B unit to source (swizzle)
    const __bf16* gA0 = A + (size_t)(bm * BM + wave * 32 + lr) * KDIM + ul * 8;
    const __bf16* gB0 = B + (size_t)(bn * BN + wave * 32 + lr) * KDIM + ul * 8;
    __bf16* lA0 = &Al[(wave * 32) * BK];
    __bf16* lB0 = &Bl[(wave * 32) * BK];

    // ---- fragment indices (16x16x32: lane holds [m=lane&15][k=(lane>>4)*8+j])
    const int ml = lane & 15;
    const int kq = lane >> 4;            // 0..3
    const int sw = lane & 7;             // row & 7 for fragment rows
    const int wm = (wave & 1) * 64;
    const int wn = (wave >> 1) * 64;

    f32x4 acc[4][4] = {};

    for (int kt = 0; kt < KDIM; kt += BK) {
        __syncthreads();   // previous tile's reads done before overwrite
#pragma unroll
        for (int c = 0; c < 4; ++c) {
            __builtin_amdgcn_global_load_lds((AS1 void*)(gA0 + (size_t)c * 8 * KDIM + kt),
                                             (AS3 void*)(lA0 + c * 8 * BK), 16, 0, 0);
            __builtin_amdgcn_global_load_lds((AS1 void*)(gB0 + (size_t)c * 8 * KDIM + kt),
                                             (AS3 void*)(lB0 + c * 8 * BK), 16, 0, 0);
        }
        __syncthreads();   // drains vmcnt -> tiles complete
#pragma unroll
        for (int st = 0; st < 2; ++st) {  // 2 k-steps of 32
            const int u = ((st * 4 + kq) ^ sw) * 8;
            bf16x8 afrag[4], bfrag[4];
#pragma unroll
            for (int i = 0; i < 4; ++i) {
                afrag[i] = *(const bf16x8*)&Al[(wm + i * 16 + ml) * BK + u];
                bfrag[i] = *(const bf16x8*)&Bl[(wn + i * 16 + ml) * BK + u];
            }
#pragma unroll
            for (int i = 0; i < 4; ++i)
#pragma unroll
                for (int j = 0; j < 4; ++j)
                    acc[i][j] = __builtin_amdgcn_mfma_f32_16x16x32_bf16(afrag[i], bfrag[j], acc[i][j], 0, 0, 0);
        }
    }

    // ---- epilogue: 16x16 C/D layout col=lane&15, row=(lane>>4)*4+reg
    const int cm0 = bm * BM + wm;
    const int cn0 = bn * BN + wn;
#pragma unroll
    for (int j = 0; j < 4; ++j) {
        const int col = cn0 + j * 16 + ml;
        const float bv = bias[col];
#pragma unroll
        for (int i = 0; i < 4; ++i) {
            const int row0 = cm0 + i * 16 + kq * 4;
#pragma unroll
            for (int r = 0; r < 4; ++r)
                C[(size_t)(row0 + r) * NDIM + col] = acc[i][j][r] + bv;
        }
    }
}

extern "C" void kernel_launch(void* const* d_in, const int* in_sizes, int n_in,
                              void* d_out, int out_size, void* d_ws, size_t ws_size,
                              hipStream_t stream) {
    const float* x     = (const float*)d_in[0];
    const float* theta = (const float*)d_in[1];
    const float* W1    = (const float*)d_in[2];
    const float* b1    = (const float*)d_in[3];
    const float* W2    = (const float*)d_in[4];
    const float* b2    = (const float*)d_in[5];
    float* out = (float*)d_out;

    __bf16* H   = (__bf16*)d_ws;                                    // 128 MiB
    __bf16* W2b = (__bf16*)((char*)d_ws + (size_t)MDIM * KDIM * 2); // + 8 MiB

    conv_w2_kernel<<<(KDIM * NDIM) / (256 * 8), 256, 0, stream>>>(W2, W2b);
    qh_kernel<<<MDIM / QROWS, 256, 0, stream>>>(x, theta, W1, b1, H);
    gemm_bt_kernel<<<(MDIM / BM) * (NDIM / BN), 256, 0, stream>>>(H, W2b, b2, out);
}